// Round 1
// baseline (383.219 us; speedup 1.0000x reference)
//
#include <hip/hip_runtime.h>

// VQ-VAE vector quantizer, MI355X fp32 baseline.
// z: (32, 256, 32, 32) fp32 ; embedding: (1024, 256) fp32
// out: [0, 8388608) quant_z (N,C,H,W) ; [8388608] vq_loss ; [8388609] commit_loss
//
// Identities used:
//   argmin_k ||z-e_k||^2 = argmin_k ( ||e_k||^2 - 2 z.e_k )
//   vq_loss = mean((z-quant)^2) = (sum_m d_min(m)) / (M*C),  commit = 0.25*vq_loss
//
// ws layout (floats): [0,1024) eNorm ; [1024] loss accumulator ; ints at +2048: idx[32768]

#define NUM_E 1024
#define CDIM  256
#define HWDIM 1024           // 32*32
#define NBATCH 32
#define M_TOTAL (NBATCH * HWDIM)  // 32768
#define TM 64
#define TK 128
#define KC 8

__global__ void vq_prep_kernel(const float* __restrict__ E, float* __restrict__ ws) {
    int k = blockIdx.x * blockDim.x + threadIdx.x;   // 0..1023
    if (k < NUM_E) {
        const float4* row = (const float4*)(E + (size_t)k * CDIM);
        float s = 0.f;
        #pragma unroll 8
        for (int i = 0; i < CDIM / 4; ++i) {
            float4 v = row[i];
            s += v.x * v.x + v.y * v.y + v.z * v.z + v.w * v.w;
        }
        ws[k] = s;
    }
    if (blockIdx.x == 0 && threadIdx.x == 0) ws[1024] = 0.f;  // zero loss accumulator
}

__global__ __launch_bounds__(256, 2)
void vq_argmin_kernel(const float* __restrict__ z, const float* __restrict__ E,
                      float* __restrict__ ws) {
    __shared__ float zs[KC][TM];      // z chunk:  [c][row]
    __shared__ float es[KC][TK];      // E chunk:  [c][k]
    __shared__ float znLds[KC][TM];   // partial |z|^2 per (c-residue, row)
    __shared__ float enormS[TK];
    __shared__ float bestS[TM];

    const int t   = threadIdx.x;
    const int m0  = blockIdx.x * TM;        // first row of this block
    const int n   = m0 >> 10;               // batch index (64 | 1024)
    const int hw0 = m0 & 1023;
    const float* zbase = z + (size_t)n * CDIM * HWDIM + hw0;

    // compute-tile mapping: 16 k-groups x 16 row-groups
    const int tk  = t & 15;       // k-group   -> 8 codes
    const int tr  = t >> 4;       // row-group -> 4 rows
    const int r0  = tr * 4;
    const int kk0 = tk * 8;

    // z-staging mapping: 2 consecutive hw per thread, c-residue = t>>5
    const int scc = t >> 5;             // 0..7
    const int shw = (t & 31) * 2;       // 0..62
    // E-staging mapping: float4 of one code row
    const int ek    = t >> 1;           // 0..127
    const int epart = (t & 1) * 4;      // 0 or 4

    float best[4];
    int   bidx[4];
    #pragma unroll
    for (int i = 0; i < 4; ++i) { best[i] = 3.4e38f; bidx[i] = 0; }

    float znp0 = 0.f, znp1 = 0.f;       // |z|^2 partials for rows shw, shw+1

    const float* eNorm = ws;

    for (int kt = 0; kt < NUM_E / TK; ++kt) {
        const int kbase = kt * TK;
        if (t < TK) enormS[t] = eNorm[kbase + t];

        float acc[4][8];
        #pragma unroll
        for (int i = 0; i < 4; ++i)
            #pragma unroll
            for (int j = 0; j < 8; ++j) acc[i][j] = 0.f;

        for (int c0 = 0; c0 < CDIM; c0 += KC) {
            __syncthreads();
            // stage z chunk (coalesced float2 along hw)
            const float2 zv = *(const float2*)(zbase + (size_t)(c0 + scc) * HWDIM + shw);
            zs[scc][shw]     = zv.x;
            zs[scc][shw + 1] = zv.y;
            if (kt == 0) { znp0 += zv.x * zv.x; znp1 += zv.y * zv.y; }
            // stage E chunk (float4 along c)
            const float4 ev = *(const float4*)(E + (size_t)(kbase + ek) * CDIM + c0 + epart);
            es[epart + 0][ek] = ev.x;
            es[epart + 1][ek] = ev.y;
            es[epart + 2][ek] = ev.z;
            es[epart + 3][ek] = ev.w;
            __syncthreads();
            #pragma unroll
            for (int cc = 0; cc < KC; ++cc) {
                float4 a  = *(const float4*)&zs[cc][r0];
                float4 b0 = *(const float4*)&es[cc][kk0];
                float4 b1 = *(const float4*)&es[cc][kk0 + 4];
                float av[4] = {a.x, a.y, a.z, a.w};
                float bv[8] = {b0.x, b0.y, b0.z, b0.w, b1.x, b1.y, b1.z, b1.w};
                #pragma unroll
                for (int i = 0; i < 4; ++i)
                    #pragma unroll
                    for (int j = 0; j < 8; ++j)
                        acc[i][j] = fmaf(av[i], bv[j], acc[i][j]);
            }
        }

        // fold this K-tile into running argmin (ascending k order, strict < => first min)
        #pragma unroll
        for (int j = 0; j < 8; ++j) {
            const float en = enormS[kk0 + j];
            const int   kg = kbase + kk0 + j;
            #pragma unroll
            for (int i = 0; i < 4; ++i) {
                const float s = en - 2.f * acc[i][j];
                if (s < best[i]) { best[i] = s; bidx[i] = kg; }
            }
        }
        if (kt == 0) {                 // store |z|^2 partials once
            znLds[scc][shw]     = znp0;
            znLds[scc][shw + 1] = znp1;
        }
        __syncthreads();               // protect enormS for next K-tile
    }

    // reduce argmin across the 16 k-group lanes (they are 16 consecutive lanes)
    #pragma unroll
    for (int i = 0; i < 4; ++i) {
        #pragma unroll
        for (int m = 8; m >= 1; m >>= 1) {
            float ob = __shfl_xor(best[i], m);
            int   oi = __shfl_xor(bidx[i], m);
            if (ob < best[i] || (ob == best[i] && oi < bidx[i])) { best[i] = ob; bidx[i] = oi; }
        }
    }
    int* idxOut = (int*)(ws + 2048);
    if (tk == 0) {
        #pragma unroll
        for (int i = 0; i < 4; ++i) {
            idxOut[m0 + r0 + i] = bidx[i];
            bestS[r0 + i]       = best[i];
        }
    }
    __syncthreads();

    // block loss partial: sum over rows of |z|^2 + min_score, wave-0 reduce, one atomic
    if (t < TM) {
        float s = 0.f;
        #pragma unroll
        for (int cc = 0; cc < KC; ++cc) s += znLds[cc][t];
        float d = s + bestS[t];
        #pragma unroll
        for (int m = 32; m >= 1; m >>= 1) d += __shfl_xor(d, m);
        if (t == 0) atomicAdd(ws + 1024, d);
    }
}

__global__ void vq_gather_kernel(const float* __restrict__ E, const float* __restrict__ ws,
                                 float* __restrict__ out) {
    const int* idx = (const int*)(ws + 2048);
    int tid  = blockIdx.x * blockDim.x + threadIdx.x;  // 0 .. 2097151
    int base = tid * 4;                                // 4 consecutive hw
    int hw = base & 1023;
    int c  = (base >> 10) & 255;
    int n  = base >> 18;
    int m  = (n << 10) + hw;
    float4 o;
    o.x = E[(size_t)idx[m + 0] * CDIM + c];
    o.y = E[(size_t)idx[m + 1] * CDIM + c];
    o.z = E[(size_t)idx[m + 2] * CDIM + c];
    o.w = E[(size_t)idx[m + 3] * CDIM + c];
    *(float4*)(out + base) = o;
}

__global__ void vq_finalize_kernel(const float* __restrict__ ws, float* __restrict__ out) {
    if (threadIdx.x == 0 && blockIdx.x == 0) {
        float L = ws[1024] * (1.0f / 8388608.0f);   // / (M_TOTAL * CDIM), exact pow2
        out[8388608] = L;
        out[8388609] = 0.25f * L;
    }
}

extern "C" void kernel_launch(void* const* d_in, const int* in_sizes, int n_in,
                              void* d_out, int out_size, void* d_ws, size_t ws_size,
                              hipStream_t stream) {
    const float* z   = (const float*)d_in[0];
    const float* E   = (const float*)d_in[1];
    float*       out = (float*)d_out;
    float*       ws  = (float*)d_ws;

    vq_prep_kernel<<<NUM_E / 256, 256, 0, stream>>>(E, ws);
    vq_argmin_kernel<<<M_TOTAL / TM, 256, 0, stream>>>(z, E, ws);
    vq_gather_kernel<<<(M_TOTAL * CDIM / 4) / 256, 256, 0, stream>>>(E, ws, out);
    vq_finalize_kernel<<<1, 64, 0, stream>>>(ws, out);
}

// Round 2
// 167.412 us; speedup vs baseline: 2.2891x; 2.2891x over previous
//
#include <hip/hip_runtime.h>
#include <stdint.h>

// VQ-VAE vector quantizer, MI355X — bf16 MFMA scores + 2-stage argmin.
// z: (32, 256, 32, 32) fp32 ; embedding: (1024, 256) fp32
// out: [0, 8388608) quant_z (N,C,H,W) ; [8388608] vq_loss ; [8388609] commit_loss
//
//   argmin_k ||z-e_k||^2 = argmin_k ( ||e_k||^2 - 2 z.e_k )   [scores in bf16 MFMA]
//   vq_loss = (sum_m (||z_m||^2 + s_min(m))) / (M*C), commit = 0.25*vq_loss

#define CDIM  256
#define M_TOTAL 32768

// ws byte offsets (total ~19.7 MB)
#define WS_ZB     0u           // bf16[32768][256]
#define WS_EB     16777216u    // bf16[1024][256]
#define WS_ENORM  17301504u    // f32[1024]
#define WS_ZNORM  17305600u    // f32[32768]
#define WS_IDX    17436672u    // i32[32768]
#define WS_PART   17567744u    // float2[8][32768]
#define WS_LOSS   19664896u    // f32

typedef __attribute__((ext_vector_type(8))) short bf16x8;
typedef __attribute__((ext_vector_type(4))) float f32x4;

__device__ inline unsigned short f2bf(float f) {
  uint32_t u = __float_as_uint(f);
  return (unsigned short)((u + 0x7FFFu + ((u >> 16) & 1u)) >> 16);
}

__device__ inline void load16(const void* g, void* l) {
  __builtin_amdgcn_global_load_lds((const __attribute__((address_space(1))) void*)g,
                                   (__attribute__((address_space(3))) void*)l, 16, 0, 0);
}

// E -> bf16 Eb + eNorm ; also zero loss accumulator. 256 blocks x 256 thr.
__global__ void vq_prep_e(const float* __restrict__ E, char* __restrict__ ws) {
  const int w = threadIdx.x >> 6, l = threadIdx.x & 63;
  const int row = blockIdx.x * 4 + w;
  const float4 v = *(const float4*)(E + (size_t)row * CDIM + l * 4);
  ushort4 b;
  b.x = f2bf(v.x); b.y = f2bf(v.y); b.z = f2bf(v.z); b.w = f2bf(v.w);
  *(ushort4*)(ws + WS_EB + (size_t)row * 512 + l * 8) = b;
  float s = v.x * v.x + v.y * v.y + v.z * v.z + v.w * v.w;
  #pragma unroll
  for (int m = 32; m >= 1; m >>= 1) s += __shfl_xor(s, m);
  if (l == 0) ((float*)(ws + WS_ENORM))[row] = s;
  if (blockIdx.x == 0 && threadIdx.x == 0) *((float*)(ws + WS_LOSS)) = 0.f;
}

// z (N,C,H,W) -> zb bf16 [M][C] (transposed) + zNorm fp32. 1024 blocks x 256 thr.
__global__ void vq_prep_z(const float* __restrict__ z, char* __restrict__ ws) {
  __shared__ float tile[32][33];
  __shared__ float psum[8][33];
  const int t = threadIdx.x;
  const int n = blockIdx.x >> 5, hw0 = (blockIdx.x & 31) * 32;
  const int hw = t & 31, cw = t >> 5;            // cw 0..7
  unsigned short* zb = (unsigned short*)(ws + WS_ZB);
  const float* zsrc = z + (size_t)n * (CDIM * 1024) + hw0 + hw;
  float acc = 0.f;
  for (int c0 = 0; c0 < CDIM; c0 += 32) {
    __syncthreads();
    #pragma unroll
    for (int j = 0; j < 4; ++j) {
      int ci = cw + 8 * j;
      float v = zsrc[(size_t)(c0 + ci) * 1024];
      tile[ci][hw] = v;
      acc += v * v;
    }
    __syncthreads();
    const int c2 = (t & 15) * 2, h2 = t >> 4;    // write bf16x2, coalesced 64B runs
    #pragma unroll
    for (int j = 0; j < 2; ++j) {
      int hh = h2 + 16 * j;
      uint32_t pk = (uint32_t)f2bf(tile[c2][hh]) | ((uint32_t)f2bf(tile[c2 + 1][hh]) << 16);
      *(uint32_t*)(zb + (size_t)(n * 1024 + hw0 + hh) * CDIM + c0 + c2) = pk;
    }
  }
  psum[cw][hw] = acc;
  __syncthreads();
  if (t < 32) {
    float s = 0.f;
    #pragma unroll
    for (int j = 0; j < 8; ++j) s += psum[j][t];
    ((float*)(ws + WS_ZNORM))[n * 1024 + hw0 + t] = s;
  }
}

// Scores + per-block argmin. Grid 2048: mt = bx&255 (128 rows), ct = bx>>8 (128 codes).
// LDS: zs/es [128 rows][64 c] bf16, XOR-granule-swizzled: granule i = r*8 + (g ^ (r&7)).
__global__ __launch_bounds__(256, 3)
void vq_scores(char* __restrict__ ws) {
  __shared__ alignas(16) unsigned short zs[128 * 64];
  __shared__ alignas(16) unsigned short es[128 * 64];
  const int t = threadIdx.x, w = t >> 6, l = t & 63;
  const int mt = blockIdx.x & 255, ct = blockIdx.x >> 8;
  const int m0 = mt * 128, k0codes = ct * 128;
  const char* zb = ws + WS_ZB;
  const char* Eb = ws + WS_EB;
  const float* eNormF = (const float*)(ws + WS_ENORM);

  const int wr = (w & 1) * 64, wc = (w >> 1) * 64;   // wave tile 64x64
  f32x4 acc[4][4];
  #pragma unroll
  for (int a = 0; a < 4; ++a)
    #pragma unroll
    for (int b = 0; b < 4; ++b) acc[a][b] = (f32x4){0.f, 0.f, 0.f, 0.f};

  for (int kk = 0; kk < 4; ++kk) {                   // BK = 64 over CDIM=256
    #pragma unroll
    for (int j = 0; j < 4; ++j) {
      const int i = (j * 4 + w) * 64 + l;            // granule index 0..1023
      const int r = i >> 3;
      const int g = (i & 7) ^ (r & 7);
      load16(zb + (size_t)(m0 + r) * 512 + kk * 128 + g * 16,
             (char*)zs + (j * 4 + w) * 1024);
      load16(Eb + (size_t)(k0codes + r) * 512 + kk * 128 + g * 16,
             (char*)es + (j * 4 + w) * 1024);
    }
    __syncthreads();
    #pragma unroll
    for (int k2 = 0; k2 < 2; ++k2) {                 // two K=32 substeps
      const int g = k2 * 4 + (l >> 4);
      bf16x8 af[4], bfr[4];
      #pragma unroll
      for (int rs = 0; rs < 4; ++rs) {
        const int r = wr + rs * 16 + (l & 15);
        af[rs] = *(const bf16x8*)((const char*)zs + ((r * 8 + (g ^ (r & 7))) * 16));
      }
      #pragma unroll
      for (int cs = 0; cs < 4; ++cs) {
        const int q = wc + cs * 16 + (l & 15);
        bfr[cs] = *(const bf16x8*)((const char*)es + ((q * 8 + (g ^ (q & 7))) * 16));
      }
      #pragma unroll
      for (int rs = 0; rs < 4; ++rs)
        #pragma unroll
        for (int cs = 0; cs < 4; ++cs)
          acc[rs][cs] = __builtin_amdgcn_mfma_f32_16x16x32_bf16(af[rs], bfr[cs], acc[rs][cs], 0, 0, 0);
    }
    __syncthreads();
  }

  // epilogue: s = ||e||^2 - 2 z.e ; argmin over this block's 128 codes
  float eN[4];
  #pragma unroll
  for (int cs = 0; cs < 4; ++cs) eN[cs] = eNormF[k0codes + wc + cs * 16 + (l & 15)];

  float bb[4][4]; int bi[4][4];
  #pragma unroll
  for (int rs = 0; rs < 4; ++rs)
    #pragma unroll
    for (int i = 0; i < 4; ++i) { bb[rs][i] = 3.4e38f; bi[rs][i] = 0; }
  #pragma unroll
  for (int cs = 0; cs < 4; ++cs) {                    // ascending code order
    const int code = k0codes + wc + cs * 16 + (l & 15);
    #pragma unroll
    for (int rs = 0; rs < 4; ++rs)
      #pragma unroll
      for (int i = 0; i < 4; ++i) {
        const float s = eN[cs] - 2.f * acc[rs][cs][i];
        if (s < bb[rs][i]) { bb[rs][i] = s; bi[rs][i] = code; }
      }
  }
  // reduce across the 16 lanes (l&15) holding different codes for the same rows
  #pragma unroll
  for (int rs = 0; rs < 4; ++rs)
    #pragma unroll
    for (int i = 0; i < 4; ++i)
      #pragma unroll
      for (int m = 8; m >= 1; m >>= 1) {
        float ob = __shfl_xor(bb[rs][i], m);
        int   oi = __shfl_xor(bi[rs][i], m);
        if (ob < bb[rs][i] || (ob == bb[rs][i] && oi < bi[rs][i])) { bb[rs][i] = ob; bi[rs][i] = oi; }
      }
  if ((l & 15) == 0) {
    float2* part = (float2*)(ws + WS_PART);
    #pragma unroll
    for (int rs = 0; rs < 4; ++rs)
      #pragma unroll
      for (int i = 0; i < 4; ++i) {
        const int m = m0 + wr + rs * 16 + (l >> 4) * 4 + i;
        float2 v; v.x = bb[rs][i]; v.y = __int_as_float(bi[rs][i]);
        part[(size_t)ct * M_TOTAL + m] = v;
      }
  }
}

// Combine 8 per-block candidates -> final idx + loss partial. 128 blocks x 256 thr.
__global__ void vq_combine(char* __restrict__ ws) {
  const int m = blockIdx.x * 256 + threadIdx.x;
  const float2* part = (const float2*)(ws + WS_PART);
  float best = 3.4e38f; int bi = 0;
  #pragma unroll
  for (int j = 0; j < 8; ++j) {
    const float2 p = part[(size_t)j * M_TOTAL + m];
    const int pi = __float_as_int(p.y);
    if (p.x < best || (p.x == best && pi < bi)) { best = p.x; bi = pi; }
  }
  ((int*)(ws + WS_IDX))[m] = bi;
  float d = ((const float*)(ws + WS_ZNORM))[m] + best;
  #pragma unroll
  for (int s = 32; s >= 1; s >>= 1) d += __shfl_xor(d, s);
  if ((threadIdx.x & 63) == 0) atomicAdd((float*)(ws + WS_LOSS), d);
}

// quant_z gather: out[n][c][hw] = E[idx[n*1024+hw]][c]. 8192 blocks x 256 thr.
__global__ void vq_gather(const float* __restrict__ E, const char* __restrict__ ws,
                          float* __restrict__ out) {
  const int* idx = (const int*)(ws + WS_IDX);
  const int tid = blockIdx.x * 256 + threadIdx.x;
  const int base = tid * 4;
  const int hw = base & 1023;
  const int c  = (base >> 10) & 255;
  const int n  = base >> 18;
  const int m  = (n << 10) + hw;
  float4 o;
  o.x = E[(size_t)idx[m + 0] * CDIM + c];
  o.y = E[(size_t)idx[m + 1] * CDIM + c];
  o.z = E[(size_t)idx[m + 2] * CDIM + c];
  o.w = E[(size_t)idx[m + 3] * CDIM + c];
  *(float4*)(out + base) = o;
}

__global__ void vq_finalize(const char* __restrict__ ws, float* __restrict__ out) {
  if (threadIdx.x == 0 && blockIdx.x == 0) {
    const float L = *((const float*)(ws + WS_LOSS)) * (1.0f / 8388608.0f);
    out[8388608] = L;
    out[8388609] = 0.25f * L;
  }
}

extern "C" void kernel_launch(void* const* d_in, const int* in_sizes, int n_in,
                              void* d_out, int out_size, void* d_ws, size_t ws_size,
                              hipStream_t stream) {
  const float* z = (const float*)d_in[0];
  const float* E = (const float*)d_in[1];
  float* out = (float*)d_out;
  char*  ws  = (char*)d_ws;

  vq_prep_e <<<256, 256, 0, stream>>>(E, ws);
  vq_prep_z <<<1024, 256, 0, stream>>>(z, ws);
  vq_scores <<<2048, 256, 0, stream>>>(ws);
  vq_combine<<<128, 256, 0, stream>>>(ws);
  vq_gather <<<8192, 256, 0, stream>>>(E, ws, out);
  vq_finalize<<<1, 64, 0, stream>>>(ws, out);
}

// Round 3
// 145.034 us; speedup vs baseline: 2.6423x; 1.1543x over previous
//
#include <hip/hip_runtime.h>
#include <stdint.h>

// VQ-VAE vector quantizer, MI355X — bf16 MFMA scores + fused combine/gather.
// z: (32, 256, 32, 32) fp32 ; embedding: (1024, 256) fp32
// out: [0, 8388608) quant_z (N,C,H,W) ; [8388608] vq_loss ; [8388609] commit_loss
//
//   argmin_k ||z-e_k||^2 = argmin_k ( ||e_k||^2 - 2 z.e_k )   [scores in bf16 MFMA]
//   vq_loss = (sum_m (||z_m||^2 + s_min(m))) / (M*C), commit = 0.25*vq_loss

#define CDIM  256
#define M_TOTAL 32768

// ws byte offsets
#define WS_ZB     0u           // bf16[32768][256]
#define WS_EB     16777216u    // bf16[1024][256]
#define WS_ENORM  17301504u    // f32[1024]
#define WS_ZNORM  17305600u    // f32[32768]
#define WS_PART   17567744u    // float2[8][32768]
#define WS_LOSS   19664896u    // f32

typedef __attribute__((ext_vector_type(8))) short bf16x8;
typedef __attribute__((ext_vector_type(4))) float f32x4;

__device__ inline unsigned short f2bf(float f) {
  uint32_t u = __float_as_uint(f);
  return (unsigned short)((u + 0x7FFFu + ((u >> 16) & 1u)) >> 16);
}

__device__ inline void load16(const void* g, void* l) {
  __builtin_amdgcn_global_load_lds((const __attribute__((address_space(1))) void*)g,
                                   (__attribute__((address_space(3))) void*)l, 16, 0, 0);
}

// Fused prep: blocks [0,256) -> E bf16 + eNorm ; blocks [256,1280) -> z transpose/bf16 + zNorm.
__global__ void vq_prep(const float* __restrict__ z, const float* __restrict__ E,
                        char* __restrict__ ws) {
  __shared__ float tile[32][33];
  __shared__ float psum[8][33];
  const int t = threadIdx.x;
  if (blockIdx.x < 256) {
    const int w = t >> 6, l = t & 63;
    const int row = blockIdx.x * 4 + w;
    const float4 v = *(const float4*)(E + (size_t)row * CDIM + l * 4);
    ushort4 b;
    b.x = f2bf(v.x); b.y = f2bf(v.y); b.z = f2bf(v.z); b.w = f2bf(v.w);
    *(ushort4*)(ws + WS_EB + (size_t)row * 512 + l * 8) = b;
    float s = v.x * v.x + v.y * v.y + v.z * v.z + v.w * v.w;
    #pragma unroll
    for (int m = 32; m >= 1; m >>= 1) s += __shfl_xor(s, m);
    if (l == 0) ((float*)(ws + WS_ENORM))[row] = s;
    if (blockIdx.x == 0 && t == 0) *((float*)(ws + WS_LOSS)) = 0.f;
    return;
  }
  const int bz = blockIdx.x - 256;
  const int n = bz >> 5, hw0 = (bz & 31) * 32;
  const int hw = t & 31, cw = t >> 5;            // cw 0..7
  unsigned short* zb = (unsigned short*)(ws + WS_ZB);
  const float* zsrc = z + (size_t)n * (CDIM * 1024) + hw0 + hw;
  float acc = 0.f;
  for (int c0 = 0; c0 < CDIM; c0 += 32) {
    __syncthreads();
    #pragma unroll
    for (int j = 0; j < 4; ++j) {
      int ci = cw + 8 * j;
      float v = zsrc[(size_t)(c0 + ci) * 1024];
      tile[ci][hw] = v;
      acc += v * v;
    }
    __syncthreads();
    const int c2 = (t & 15) * 2, h2 = t >> 4;    // write bf16x2, coalesced 64B runs
    #pragma unroll
    for (int j = 0; j < 2; ++j) {
      int hh = h2 + 16 * j;
      uint32_t pk = (uint32_t)f2bf(tile[c2][hh]) | ((uint32_t)f2bf(tile[c2 + 1][hh]) << 16);
      *(uint32_t*)(zb + (size_t)(n * 1024 + hw0 + hh) * CDIM + c0 + c2) = pk;
    }
  }
  psum[cw][hw] = acc;
  __syncthreads();
  if (t < 32) {
    float s = 0.f;
    #pragma unroll
    for (int j = 0; j < 8; ++j) s += psum[j][t];
    ((float*)(ws + WS_ZNORM))[n * 1024 + hw0 + t] = s;
  }
}

// Scores + per-block argmin. Grid 2048: mt = bx&255 (128 rows), ct = bx>>8 (128 codes).
// LDS: zs/es [128 rows][64 c] bf16, XOR-granule-swizzled: granule i = r*8 + (g ^ (r&7)).
__global__ __launch_bounds__(256, 3)
void vq_scores(char* __restrict__ ws) {
  __shared__ alignas(16) unsigned short zs[128 * 64];
  __shared__ alignas(16) unsigned short es[128 * 64];
  const int t = threadIdx.x, w = t >> 6, l = t & 63;
  const int mt = blockIdx.x & 255, ct = blockIdx.x >> 8;
  const int m0 = mt * 128, k0codes = ct * 128;
  const char* zb = ws + WS_ZB;
  const char* Eb = ws + WS_EB;
  const float* eNormF = (const float*)(ws + WS_ENORM);

  const int wr = (w & 1) * 64, wc = (w >> 1) * 64;   // wave tile 64x64
  f32x4 acc[4][4];
  #pragma unroll
  for (int a = 0; a < 4; ++a)
    #pragma unroll
    for (int b = 0; b < 4; ++b) acc[a][b] = (f32x4){0.f, 0.f, 0.f, 0.f};

  for (int kk = 0; kk < 4; ++kk) {                   // BK = 64 over CDIM=256
    #pragma unroll
    for (int j = 0; j < 4; ++j) {
      const int i = (j * 4 + w) * 64 + l;            // granule index 0..1023
      const int r = i >> 3;
      const int g = (i & 7) ^ (r & 7);
      load16(zb + (size_t)(m0 + r) * 512 + kk * 128 + g * 16,
             (char*)zs + (j * 4 + w) * 1024);
      load16(Eb + (size_t)(k0codes + r) * 512 + kk * 128 + g * 16,
             (char*)es + (j * 4 + w) * 1024);
    }
    __syncthreads();
    #pragma unroll
    for (int k2 = 0; k2 < 2; ++k2) {                 // two K=32 substeps
      const int g = k2 * 4 + (l >> 4);
      bf16x8 af[4], bfr[4];
      #pragma unroll
      for (int rs = 0; rs < 4; ++rs) {
        const int r = wr + rs * 16 + (l & 15);
        af[rs] = *(const bf16x8*)((const char*)zs + ((r * 8 + (g ^ (r & 7))) * 16));
      }
      #pragma unroll
      for (int cs = 0; cs < 4; ++cs) {
        const int q = wc + cs * 16 + (l & 15);
        bfr[cs] = *(const bf16x8*)((const char*)es + ((q * 8 + (g ^ (q & 7))) * 16));
      }
      #pragma unroll
      for (int rs = 0; rs < 4; ++rs)
        #pragma unroll
        for (int cs = 0; cs < 4; ++cs)
          acc[rs][cs] = __builtin_amdgcn_mfma_f32_16x16x32_bf16(af[rs], bfr[cs], acc[rs][cs], 0, 0, 0);
    }
    __syncthreads();
  }

  // epilogue: s = ||e||^2 - 2 z.e ; argmin over this block's 128 codes
  float eN[4];
  #pragma unroll
  for (int cs = 0; cs < 4; ++cs) eN[cs] = eNormF[k0codes + wc + cs * 16 + (l & 15)];

  float bb[4][4]; int bi[4][4];
  #pragma unroll
  for (int rs = 0; rs < 4; ++rs)
    #pragma unroll
    for (int i = 0; i < 4; ++i) { bb[rs][i] = 3.4e38f; bi[rs][i] = 0; }
  #pragma unroll
  for (int cs = 0; cs < 4; ++cs) {                    // ascending code order
    const int code = k0codes + wc + cs * 16 + (l & 15);
    #pragma unroll
    for (int rs = 0; rs < 4; ++rs)
      #pragma unroll
      for (int i = 0; i < 4; ++i) {
        const float s = eN[cs] - 2.f * acc[rs][cs][i];
        if (s < bb[rs][i]) { bb[rs][i] = s; bi[rs][i] = code; }
      }
  }
  // reduce across the 16 lanes (l&15) holding different codes for the same rows
  #pragma unroll
  for (int rs = 0; rs < 4; ++rs)
    #pragma unroll
    for (int i = 0; i < 4; ++i)
      #pragma unroll
      for (int m = 8; m >= 1; m >>= 1) {
        float ob = __shfl_xor(bb[rs][i], m);
        int   oi = __shfl_xor(bi[rs][i], m);
        if (ob < bb[rs][i] || (ob == bb[rs][i] && oi < bi[rs][i])) { bb[rs][i] = ob; bi[rs][i] = oi; }
      }
  if ((l & 15) == 0) {
    float2* part = (float2*)(ws + WS_PART);
    #pragma unroll
    for (int rs = 0; rs < 4; ++rs)
      #pragma unroll
      for (int i = 0; i < 4; ++i) {
        const int m = m0 + wr + rs * 16 + (l >> 4) * 4 + i;
        float2 v; v.x = bb[rs][i]; v.y = __int_as_float(bi[rs][i]);
        part[(size_t)ct * M_TOTAL + m] = v;
      }
  }
}

// Fused combine + gather. Grid 1024: block = (n, 32-hw tile), all 256 channels.
// Phase A: 8-way argmin combine for 32 rows + loss partial.
// Phase B: coalesced E-row reads -> LDS tile[c][hw] (padded).
// Phase C: float4 writes to out, 128-B contiguous segments.
__global__ __launch_bounds__(256, 4)
void vq_gather(const float* __restrict__ E, char* __restrict__ ws,
               float* __restrict__ out) {
  __shared__ float tile[256][33];
  __shared__ int idxS[32];
  const int t = threadIdx.x;
  const int n = blockIdx.x >> 5, hw0 = (blockIdx.x & 31) * 32;
  const int mbase = n * 1024 + hw0;

  if (t < 32) {
    const float2* part = (const float2*)(ws + WS_PART);
    const int m = mbase + t;
    float best = 3.4e38f; int bi = 0;
    #pragma unroll
    for (int j = 0; j < 8; ++j) {
      const float2 p = part[(size_t)j * M_TOTAL + m];
      const int pi = __float_as_int(p.y);
      if (p.x < best || (p.x == best && pi < bi)) { best = p.x; bi = pi; }
    }
    idxS[t] = bi;
    float d = ((const float*)(ws + WS_ZNORM))[m] + best;
    #pragma unroll
    for (int s = 16; s >= 1; s >>= 1) d += __shfl_xor(d, s);
    if (t == 0) atomicAdd((float*)(ws + WS_LOSS), d);
  }
  __syncthreads();

  // Phase B: each of 32 rows read by 8 lanes, 8 float4 per lane (coalesced 128B runs)
  const int hw = t >> 3, q = t & 7;
  const float4* erow = (const float4*)(E + (size_t)idxS[hw] * CDIM);
  #pragma unroll
  for (int j = 0; j < 8; ++j) {
    const int p = q + j * 8;          // float4 index 0..63 -> c = p*4
    const float4 v = erow[p];
    tile[p * 4 + 0][hw] = v.x;
    tile[p * 4 + 1][hw] = v.y;
    tile[p * 4 + 2][hw] = v.z;
    tile[p * 4 + 3][hw] = v.w;
  }
  __syncthreads();

  // Phase C: out[n][c][hw0+hw4..+3], lanes cover (c, hw4) -> contiguous 128B per 8 lanes
  float* obase = out + (size_t)n * (CDIM * 1024) + hw0;
  const int hw4 = (t & 7) * 4, c0 = t >> 3;
  #pragma unroll
  for (int j = 0; j < 8; ++j) {
    const int c = c0 + j * 32;
    float4 v;
    v.x = tile[c][hw4 + 0];
    v.y = tile[c][hw4 + 1];
    v.z = tile[c][hw4 + 2];
    v.w = tile[c][hw4 + 3];
    *(float4*)(obase + (size_t)c * 1024 + hw4) = v;
  }
}

__global__ void vq_finalize(const char* __restrict__ ws, float* __restrict__ out) {
  if (threadIdx.x == 0 && blockIdx.x == 0) {
    const float L = *((const float*)(ws + WS_LOSS)) * (1.0f / 8388608.0f);
    out[8388608] = L;
    out[8388609] = 0.25f * L;
  }
}

extern "C" void kernel_launch(void* const* d_in, const int* in_sizes, int n_in,
                              void* d_out, int out_size, void* d_ws, size_t ws_size,
                              hipStream_t stream) {
  const float* z = (const float*)d_in[0];
  const float* E = (const float*)d_in[1];
  float* out = (float*)d_out;
  char*  ws  = (char*)d_ws;

  vq_prep   <<<1280, 256, 0, stream>>>(z, E, ws);
  vq_scores <<<2048, 256, 0, stream>>>(ws);
  vq_gather <<<1024, 256, 0, stream>>>(E, ws, out);
  vq_finalize<<<1, 64, 0, stream>>>(ws, out);
}

// Round 4
// 125.203 us; speedup vs baseline: 3.0608x; 1.1584x over previous
//
#include <hip/hip_runtime.h>
#include <stdint.h>

// VQ-VAE vector quantizer, MI355X — single resident-tile MFMA kernel.
// z: (32, 256, 32, 32) fp32 ; embedding: (1024, 256) fp32
// out: [0, 8388608) quant_z (N,C,H,W) ; [8388608] vq_loss ; [8388609] commit_loss
//
//   argmin_k ||z-e_k||^2 = argmin_k ( ||e_k||^2 - 2 z.e_k )   [bf16 MFMA scores]
//   vq_loss = (sum_m (||z_m||^2 + s_min(m))) / (M*C), commit = 0.25*vq_loss

#define CDIM  256
#define M_TOTAL 32768

// ws byte offsets
#define WS_EB     16777216u    // bf16[1024][256]
#define WS_ENORM  17301504u    // f32[1024]
#define WS_IDX    17436672u    // i32[32768]
#define WS_LOSS   19664896u    // f32

// LDS byte offsets (dynamic shared, 155136 total)
#define L_ZS     0u            // bf16 [128 rows][256 c], XOR-granule swizzle
#define L_ES     65536u        // bf16 [2][64 codes][256 c], swizzled, double buffer
#define L_ENORM  131072u       // f32[1024]
#define L_ZNP    135168u       // f32[128][2]
#define L_CAND   136192u       // float2[4][64]
#define L_TILEF  138240u       // f32[32][132]

typedef __attribute__((ext_vector_type(8))) short bf16x8;
typedef __attribute__((ext_vector_type(4))) float f32x4;

__device__ inline unsigned short f2bf(float f) {
  uint32_t u = __float_as_uint(f);
  return (unsigned short)((u + 0x7FFFu + ((u >> 16) & 1u)) >> 16);
}

__device__ inline void load16(const void* g, void* l) {
  __builtin_amdgcn_global_load_lds((const __attribute__((address_space(1))) void*)g,
                                   (__attribute__((address_space(3))) void*)l, 16, 0, 0);
}

// E -> bf16 Eb + eNorm ; zero loss. 256 blocks x 256 thr.
__global__ void vq_prep_e(const float* __restrict__ E, char* __restrict__ ws) {
  const int w = threadIdx.x >> 6, l = threadIdx.x & 63;
  const int row = blockIdx.x * 4 + w;
  const float4 v = *(const float4*)(E + (size_t)row * CDIM + l * 4);
  ushort4 b;
  b.x = f2bf(v.x); b.y = f2bf(v.y); b.z = f2bf(v.z); b.w = f2bf(v.w);
  *(ushort4*)(ws + WS_EB + (size_t)row * 512 + l * 8) = b;
  float s = v.x * v.x + v.y * v.y + v.z * v.z + v.w * v.w;
  #pragma unroll
  for (int m = 32; m >= 1; m >>= 1) s += __shfl_xor(s, m);
  if (l == 0) ((float*)(ws + WS_ENORM))[row] = s;
  if (blockIdx.x == 0 && threadIdx.x == 0) *((float*)(ws + WS_LOSS)) = 0.f;
}

// One block per CU: 128 z-rows resident; all 1024 codes streamed; argmin + loss.
__global__ __launch_bounds__(256, 1)
void vq_main(const float* __restrict__ z, char* __restrict__ ws) {
  extern __shared__ char lds[];
  unsigned short* zs = (unsigned short*)(lds + L_ZS);
  char* esb          = lds + L_ES;
  float* eNormS      = (float*)(lds + L_ENORM);
  float* znPart      = (float*)(lds + L_ZNP);
  float2* cand       = (float2*)(lds + L_CAND);
  float* tileF       = (float*)(lds + L_TILEF);

  const int t = threadIdx.x, w = t >> 6, l = t & 63;
  const int mt = blockIdx.x;                 // 0..255
  const int n = mt >> 3, hw0 = (mt & 7) << 7;
  const int m0 = mt << 7;
  const char* Eb = ws + WS_EB;

  // per-thread staging source offsets for one es tile (swizzle baked in)
  int srcOff[8];
  #pragma unroll
  for (int i = 0; i < 8; ++i) {
    const int j = (i * 4 + w) * 64 + l;      // LDS granule 0..2047
    const int q = j >> 5;                    // code-in-tile 0..63
    const int g = (j & 31) ^ (q & 7);        // source granule (un-swizzle)
    srcOff[i] = q * 512 + g * 16;
  }
  // stage es tile 0 into buf 0 ; preload eNorm into LDS
  #pragma unroll
  for (int i = 0; i < 8; ++i)
    load16(Eb + srcOff[i], esb + (i * 4 + w) * 1024);
  load16((const char*)(ws + WS_ENORM) + (w * 64 + l) * 16, (char*)eNormS + w * 1024);

  // ---- prologue: z (c-major) -> zs (row-major bf16, swizzled) + |z|^2 ----
  const float* zb0 = z + (size_t)n * (CDIM * 1024) + hw0;
  const int cA = t >> 3;                     // c within 32-chunk
  const int hA = (t & 7) * 16;               // hw offset (4 float4)
  const int r2 = t >> 1, gsub = t & 1;
  float4 v0 = *(const float4*)(zb0 + (size_t)cA * 1024 + hA);
  float4 v1 = *(const float4*)(zb0 + (size_t)cA * 1024 + hA + 4);
  float4 v2 = *(const float4*)(zb0 + (size_t)cA * 1024 + hA + 8);
  float4 v3 = *(const float4*)(zb0 + (size_t)cA * 1024 + hA + 12);
  float znAcc = 0.f;
  for (int ci = 0; ci < 8; ++ci) {
    __syncthreads();                         // tileF free
    *(float4*)(tileF + cA * 132 + hA)      = v0;
    *(float4*)(tileF + cA * 132 + hA + 4)  = v1;
    *(float4*)(tileF + cA * 132 + hA + 8)  = v2;
    *(float4*)(tileF + cA * 132 + hA + 12) = v3;
    if (ci < 7) {
      const float* src = zb0 + (size_t)((ci + 1) * 32 + cA) * 1024 + hA;
      v0 = *(const float4*)(src);
      v1 = *(const float4*)(src + 4);
      v2 = *(const float4*)(src + 8);
      v3 = *(const float4*)(src + 12);
    }
    __syncthreads();                         // tileF ready
    float s[16];
    #pragma unroll
    for (int k = 0; k < 16; ++k) {
      s[k] = tileF[(gsub * 16 + k) * 132 + r2];
      znAcc += s[k] * s[k];
    }
    #pragma unroll
    for (int jj = 0; jj < 2; ++jj) {
      union { bf16x8 v; unsigned short u[8]; } pk;
      #pragma unroll
      for (int k = 0; k < 8; ++k) pk.u[k] = f2bf(s[jj * 8 + k]);
      const int g  = ci * 4 + gsub * 2 + jj;     // logical granule 0..31
      const int gp = g ^ (r2 & 7);
      *(bf16x8*)((char*)zs + r2 * 512 + gp * 16) = pk.v;
    }
  }
  znPart[r2 * 2 + gsub] = znAcc;
  __syncthreads();                           // zs complete (also drains tile-0 staging)

  // ---- cache A fragments in registers: 64 rows x K=256 per wave ----
  const int wrow = (w & 1) * 64, chalf = (w >> 1) * 32;
  const int lrow = l & 15, lk = l >> 4;
  bf16x8 af[4][8];
  #pragma unroll
  for (int rs = 0; rs < 4; ++rs) {
    const int r = wrow + rs * 16 + lrow;
    #pragma unroll
    for (int kg = 0; kg < 8; ++kg) {
      const int gp = (kg * 4 + lk) ^ (r & 7);
      af[rs][kg] = *(const bf16x8*)((const char*)zs + r * 512 + gp * 16);
    }
  }

  // ---- main loop: 16 tiles x 64 codes, es double-buffered ----
  float bb[4][4]; int bidx[4][4];
  #pragma unroll
  for (int rs = 0; rs < 4; ++rs)
    #pragma unroll
    for (int i = 0; i < 4; ++i) { bb[rs][i] = 3.4e38f; bidx[rs][i] = 0; }

  for (int tile = 0; tile < 16; ++tile) {
    const int cur = tile & 1;
    if (tile < 15) {                         // stage next tile
      const char* src = Eb + (size_t)(tile + 1) * 32768;
      char* dst = esb + (cur ^ 1) * 32768;
      #pragma unroll
      for (int i = 0; i < 8; ++i)
        load16(src + srcOff[i], dst + (i * 4 + w) * 1024);
    }
    f32x4 acc[4][2];
    #pragma unroll
    for (int rs = 0; rs < 4; ++rs)
      #pragma unroll
      for (int cs = 0; cs < 2; ++cs) acc[rs][cs] = (f32x4){0.f, 0.f, 0.f, 0.f};
    #pragma unroll
    for (int kg = 0; kg < 8; ++kg) {
      bf16x8 bf[2];
      #pragma unroll
      for (int cs = 0; cs < 2; ++cs) {
        const int q = chalf + cs * 16 + lrow;
        const int gp = (kg * 4 + lk) ^ (q & 7);
        bf[cs] = *(const bf16x8*)((const char*)esb + cur * 32768 + q * 512 + gp * 16);
      }
      #pragma unroll
      for (int rs = 0; rs < 4; ++rs)
        #pragma unroll
        for (int cs = 0; cs < 2; ++cs)
          acc[rs][cs] = __builtin_amdgcn_mfma_f32_16x16x32_bf16(af[rs][kg], bf[cs], acc[rs][cs], 0, 0, 0);
    }
    // fold scores into running argmin (codes ascending; strict < keeps first index)
    #pragma unroll
    for (int cs = 0; cs < 2; ++cs) {
      const int code = tile * 64 + chalf + cs * 16 + lrow;
      const float eN = eNormS[code];
      #pragma unroll
      for (int rs = 0; rs < 4; ++rs)
        #pragma unroll
        for (int i = 0; i < 4; ++i) {
          const float s = fmaf(-2.f, acc[rs][cs][i], eN);
          if (s < bb[rs][i]) { bb[rs][i] = s; bidx[rs][i] = code; }
        }
    }
    __syncthreads();                         // es[cur] consumed; next staging drained
  }

  // ---- epilogue: reduce over 16 code-lanes, cross-wave combine, loss ----
  #pragma unroll
  for (int rs = 0; rs < 4; ++rs)
    #pragma unroll
    for (int i = 0; i < 4; ++i)
      #pragma unroll
      for (int m = 8; m >= 1; m >>= 1) {
        const float ob = __shfl_xor(bb[rs][i], m);
        const int   oi = __shfl_xor(bidx[rs][i], m);
        if (ob < bb[rs][i] || (ob == bb[rs][i] && oi < bidx[rs][i])) { bb[rs][i] = ob; bidx[rs][i] = oi; }
      }
  if (lrow == 0) {
    #pragma unroll
    for (int rs = 0; rs < 4; ++rs)
      #pragma unroll
      for (int i = 0; i < 4; ++i) {
        float2 c; c.x = bb[rs][i]; c.y = __int_as_float(bidx[rs][i]);
        cand[w * 64 + rs * 16 + lk * 4 + i] = c;
      }
  }
  __syncthreads();
  if (t < 128) {
    const int half = t >> 6, rl = t & 63;
    const float2 cA0 = cand[half * 64 + rl];
    const float2 cB0 = cand[(half + 2) * 64 + rl];
    float best = cA0.x; int bi = __float_as_int(cA0.y);
    const int biB = __float_as_int(cB0.y);
    if (cB0.x < best || (cB0.x == best && biB < bi)) { best = cB0.x; bi = biB; }
    const int r = half * 64 + rl;
    ((int*)(ws + WS_IDX))[m0 + r] = bi;
    float d = znPart[r * 2] + znPart[r * 2 + 1] + best;
    #pragma unroll
    for (int m = 32; m >= 1; m >>= 1) d += __shfl_xor(d, m);
    if ((t & 63) == 0) atomicAdd((float*)(ws + WS_LOSS), d);
  }
}

// Gather quant_z: block = (n, 32-hw tile), all 256 channels, via padded LDS tile.
__global__ __launch_bounds__(256, 4)
void vq_gather(const float* __restrict__ E, const char* __restrict__ ws,
               float* __restrict__ out) {
  __shared__ float tile[256][33];
  __shared__ int idxS[32];
  const int t = threadIdx.x;
  const int n = blockIdx.x >> 5, hw0 = (blockIdx.x & 31) * 32;
  if (t < 32) idxS[t] = ((const int*)(ws + WS_IDX))[n * 1024 + hw0 + t];
  __syncthreads();

  const int hw = t >> 3, q = t & 7;
  const float4* erow = (const float4*)(E + (size_t)idxS[hw] * CDIM);
  #pragma unroll
  for (int j = 0; j < 8; ++j) {
    const int p = q + j * 8;
    const float4 v = erow[p];
    tile[p * 4 + 0][hw] = v.x;
    tile[p * 4 + 1][hw] = v.y;
    tile[p * 4 + 2][hw] = v.z;
    tile[p * 4 + 3][hw] = v.w;
  }
  __syncthreads();

  float* obase = out + (size_t)n * (CDIM * 1024) + hw0;
  const int hw4 = (t & 7) * 4, c0 = t >> 3;
  #pragma unroll
  for (int j = 0; j < 8; ++j) {
    const int c = c0 + j * 32;
    float4 v;
    v.x = tile[c][hw4 + 0];
    v.y = tile[c][hw4 + 1];
    v.z = tile[c][hw4 + 2];
    v.w = tile[c][hw4 + 3];
    *(float4*)(obase + (size_t)c * 1024 + hw4) = v;
  }
}

__global__ void vq_finalize(const char* __restrict__ ws, float* __restrict__ out) {
  if (threadIdx.x == 0 && blockIdx.x == 0) {
    const float L = *((const float*)(ws + WS_LOSS)) * (1.0f / 8388608.0f);
    out[8388608] = L;
    out[8388609] = 0.25f * L;
  }
}

extern "C" void kernel_launch(void* const* d_in, const int* in_sizes, int n_in,
                              void* d_out, int out_size, void* d_ws, size_t ws_size,
                              hipStream_t stream) {
  const float* z = (const float*)d_in[0];
  const float* E = (const float*)d_in[1];
  float* out = (float*)d_out;
  char*  ws  = (char*)d_ws;

  static const int kLds = 155136;
  (void)hipFuncSetAttribute((const void*)vq_main,
                            hipFuncAttributeMaxDynamicSharedMemorySize, kLds);

  vq_prep_e <<<256, 256, 0, stream>>>(E, ws);
  vq_main   <<<256, 256, kLds, stream>>>(z, ws);
  vq_gather <<<1024, 256, 0, stream>>>(E, ws, out);
  vq_finalize<<<1, 64, 0, stream>>>(ws, out);
}